// Round 12
// baseline (297.074 us; speedup 1.0000x reference)
//
#include <hip/hip_runtime.h>

#define S_LEN 2048
#define HIDN  2560
#define HQ_N  8
#define HKV_N 4
#define HD_N  256
#define NQKV  4096   // HQ*HD + 2*HKV*HD
#define MROWS 4096   // B*S
#define SC2   0.09016844005556021f  // HD^-0.5 * log2(e), folded into Q at producer

typedef __attribute__((ext_vector_type(8))) short bf16x8;
typedef __attribute__((ext_vector_type(4))) float f32x4;
typedef __attribute__((ext_vector_type(4))) unsigned short u16x4;

typedef const __attribute__((address_space(1))) unsigned int* gas_t;
typedef __attribute__((address_space(3))) unsigned int* las_t;
#define GLDS16(gp, lp) __builtin_amdgcn_global_load_lds((gas_t)(const void*)(gp), \
                                                        (las_t)(void*)(lp), 16, 0, 0)

static __device__ __forceinline__ float bf2f(unsigned short u) {
  unsigned int x = ((unsigned int)u) << 16;
  return __builtin_bit_cast(float, x);
}
static __device__ __forceinline__ unsigned short f2bf(float f) {
  unsigned int u = __builtin_bit_cast(unsigned int, f);
  u += 0x7fffu + ((u >> 16) & 1u);
  return (unsigned short)(u >> 16);
}

// ---------------- merged fp32 -> bf16 cast for all 5 tensors (one launch) ----------------
__global__ void cvt_all_kernel(const float* __restrict__ hid, const float* __restrict__ Wq,
                               const float* __restrict__ Wk, const float* __restrict__ Wv,
                               const float* __restrict__ Wo, unsigned short* __restrict__ Xbf,
                               unsigned short* __restrict__ Wcat,
                               unsigned short* __restrict__ Wob) {
  int i = blockIdx.x * 256 + threadIdx.x;
  const float* src;
  unsigned short* dst;
  int j;
  if (i < 2621440) { src = hid; dst = Xbf; j = i; }
  else if (i < 3932160) { src = Wq; dst = Wcat; j = i - 2621440; }
  else if (i < 4587520) { src = Wk; dst = Wcat + 5242880; j = i - 3932160; }
  else if (i < 5242880) { src = Wv; dst = Wcat + 7864320; j = i - 4587520; }
  else { src = Wo; dst = Wob; j = i - 5242880; }
  f32x4 v = ((const f32x4*)src)[j];
  u16x4 o;
  o[0] = f2bf(v[0]); o[1] = f2bf(v[1]); o[2] = f2bf(v[2]); o[3] = f2bf(v[3]);
  ((u16x4*)dst)[j] = o;
}

// ---------------- 256x256-tile pipelined GEMM, 4-phase/K-tile (R7 proven loop) ----------
// OUT_BF16=1: bf16 C (QKV). OUT_BF16=0: fp32 C (out-proj).
template <int OUT_BF16>
__global__ __launch_bounds__(512, 2) void gemm8p(const unsigned short* __restrict__ A,
                                                 const unsigned short* __restrict__ B,
                                                 void* __restrict__ C,
                                                 int M, int N, int K, int gx) {
  __shared__ unsigned short ldsw[65536];  // 2 bufs x 32768 elems (128 KB)
  const int tid = threadIdx.x;
  const int lane = tid & 63;
  const int w = tid >> 6;
  const int r = lane & 15, g = lane >> 4;
  const int wr = w >> 2, wc = w & 3;
  const int NT = K >> 6;

  const int nwg = gridDim.x;
  const int cpx = nwg >> 3;
  const int bid = blockIdx.x;
  const int sbid = (bid & 7) * cpx + (bid >> 3);
  const int bx = sbid % gx, by = sbid / gx;
  const int brow = by * 256, bcol = bx * 256;

  const int lr = lane >> 3;
  const int lc8 = ((lane & 7) ^ lr) * 8;
  const unsigned short* gA = A + (size_t)(brow + w * 16 + lr) * K + lc8;
  const unsigned short* gB = B + (size_t)(bcol + w * 16 + lr) * K + lc8;
  const size_t rK8 = (size_t)8 * K;
  const size_t rK128 = (size_t)128 * K;
  const int wl = w * 1024;

  const int sl0 = (((g ^ (r & 3)) + 4 * ((r >> 2) & 1))) * 8;
  int aoff[8], boff[4];
#pragma unroll
  for (int mf = 0; mf < 8; mf++) aoff[mf] = wr * 8192 + (mf * 16 + r) * 64 + sl0;
#pragma unroll
  for (int nf = 0; nf < 4; nf++)
    boff[nf] = 16384 + (wc >> 1) * 8192 + ((wc & 1) * 64 + nf * 16 + r) * 64 + sl0;

  f32x4 acc[8][4];
#pragma unroll
  for (int i = 0; i < 8; i++)
#pragma unroll
    for (int j = 0; j < 4; j++) acc[i][j] = (f32x4){0.f, 0.f, 0.f, 0.f};

  {
    unsigned short* b0 = ldsw;
    unsigned short* b1 = ldsw + 32768;
    GLDS16(gA, b0 + wl);                    GLDS16(gA + rK8, b0 + wl + 512);
    GLDS16(gA + rK128, b0 + 8192 + wl);     GLDS16(gA + rK128 + rK8, b0 + 8192 + wl + 512);
    GLDS16(gB, b0 + 16384 + wl);            GLDS16(gB + rK8, b0 + 16384 + wl + 512);
    GLDS16(gB + rK128, b0 + 24576 + wl);    GLDS16(gB + rK128 + rK8, b0 + 24576 + wl + 512);
    GLDS16(gA + 64, b1 + wl);               GLDS16(gA + 64 + rK8, b1 + wl + 512);
    GLDS16(gA + 64 + rK128, b1 + 8192 + wl); GLDS16(gA + 64 + rK128 + rK8, b1 + 8192 + wl + 512);
  }
  asm volatile("s_waitcnt vmcnt(4)" ::: "memory");
  __builtin_amdgcn_sched_barrier(0);
  __builtin_amdgcn_s_barrier();

  for (int u = 0; u < NT; ++u) {
    const unsigned short* cbp = ldsw + (u & 1) * 32768;
    unsigned short* cbw = ldsw + (u & 1) * 32768;
    unsigned short* obw = ldsw + ((u & 1) ^ 1) * 32768;
    const int c1 = (u + 1) * 64;
    const int c2 = (u + 2) * 64;
    const bool s1 = (u + 1) < NT, s2 = (u + 2) < NT;

    bf16x8 af0[4], bk0[4], af1[4];
#pragma unroll
    for (int mf = 0; mf < 4; mf++) af0[mf] = *(const bf16x8*)(cbp + aoff[mf]);
#pragma unroll
    for (int nf = 0; nf < 4; nf++) bk0[nf] = *(const bf16x8*)(cbp + boff[nf]);
#pragma unroll
    for (int mf = 0; mf < 4; mf++) af1[mf] = *(const bf16x8*)(cbp + aoff[4 + mf]);
    if (s1) {
      GLDS16(gB + c1, obw + 16384 + wl);
      GLDS16(gB + c1 + rK8, obw + 16384 + wl + 512);
    }
    __builtin_amdgcn_s_setprio(1);
#pragma unroll
    for (int mf = 0; mf < 4; mf++)
#pragma unroll
      for (int nf = 0; nf < 4; nf++)
        acc[mf][nf] = __builtin_amdgcn_mfma_f32_16x16x32_bf16(af0[mf], bk0[nf], acc[mf][nf], 0, 0, 0);
    __builtin_amdgcn_s_setprio(0);

    bf16x8 ag0[4], ag1[4];
#pragma unroll
    for (int mf = 0; mf < 4; mf++) ag0[mf] = *(const bf16x8*)(cbp + (aoff[mf] ^ 32));
#pragma unroll
    for (int mf = 0; mf < 4; mf++) ag1[mf] = *(const bf16x8*)(cbp + (aoff[4 + mf] ^ 32));
    if (s1) {
      GLDS16(gB + c1 + rK128, obw + 24576 + wl);
      GLDS16(gB + c1 + rK128 + rK8, obw + 24576 + wl + 512);
    }
    __builtin_amdgcn_s_setprio(1);
#pragma unroll
    for (int mf = 0; mf < 4; mf++)
#pragma unroll
      for (int nf = 0; nf < 4; nf++)
        acc[4 + mf][nf] = __builtin_amdgcn_mfma_f32_16x16x32_bf16(af1[mf], bk0[nf], acc[4 + mf][nf], 0, 0, 0);
    __builtin_amdgcn_s_setprio(0);
    asm volatile("s_waitcnt lgkmcnt(0)" ::: "memory");
    __builtin_amdgcn_sched_barrier(0);
    __builtin_amdgcn_s_barrier();

    bf16x8 bk1[4];
#pragma unroll
    for (int nf = 0; nf < 4; nf++) bk1[nf] = *(const bf16x8*)(cbp + (boff[nf] ^ 32));
    if (s2) {
      GLDS16(gA + c2, cbw + wl);
      GLDS16(gA + c2 + rK8, cbw + wl + 512);
    }
    __builtin_amdgcn_s_setprio(1);
#pragma unroll
    for (int mf = 0; mf < 4; mf++)
#pragma unroll
      for (int nf = 0; nf < 4; nf++)
        acc[mf][nf] = __builtin_amdgcn_mfma_f32_16x16x32_bf16(ag0[mf], bk1[nf], acc[mf][nf], 0, 0, 0);
    __builtin_amdgcn_s_setprio(0);

    if (s2) {
      GLDS16(gA + c2 + rK128, cbw + 8192 + wl);
      GLDS16(gA + c2 + rK128 + rK8, cbw + 8192 + wl + 512);
    }
    __builtin_amdgcn_s_setprio(1);
#pragma unroll
    for (int mf = 0; mf < 4; mf++)
#pragma unroll
      for (int nf = 0; nf < 4; nf++)
        acc[4 + mf][nf] = __builtin_amdgcn_mfma_f32_16x16x32_bf16(ag1[mf], bk1[nf], acc[4 + mf][nf], 0, 0, 0);
    __builtin_amdgcn_s_setprio(0);
    if (s2) { asm volatile("s_waitcnt vmcnt(4)" ::: "memory"); }
    else    { asm volatile("s_waitcnt vmcnt(0)" ::: "memory"); }
    __builtin_amdgcn_sched_barrier(0);
    __builtin_amdgcn_s_barrier();
  }

#pragma unroll
  for (int i = 0; i < 8; i++)
#pragma unroll
    for (int j = 0; j < 4; j++) {
      const int col = bcol + wc * 64 + j * 16 + r;
      const int rowb = brow + wr * 128 + i * 16 + g * 4;
#pragma unroll
      for (int e = 0; e < 4; e++) {
        if (OUT_BF16)
          ((unsigned short*)C)[(size_t)(rowb + e) * N + col] = f2bf(acc[i][j][e]);
        else
          ((float*)C)[(size_t)(rowb + e) * N + col] = acc[i][j][e];
      }
    }
}

// ---------------- fused RMSNorm (+weight) + RoPE (standalone, full occupancy) ----------
// q: [b][h][s][d] row-major bf16, PRE-SCALED by SC2.
// k: per-32-key tiled slabs, slot pre-swizzled: slot' = (d>>3) ^ (kr&7)
// v: per-32-key tiled slabs, slot pre-swizzled: slot' = (ks>>3) ^ ((d>>1)&3)
// RoPE symmetry: cos[d]==cos[d&127], batch-broadcast -> read batch-0 d<128 slice only.
__global__ __launch_bounds__(256) void rms_rope_kernel(
    const unsigned short* __restrict__ qkv, const float* __restrict__ cosb,
    const float* __restrict__ sinb, const float* __restrict__ qw,
    const float* __restrict__ kw, unsigned short* __restrict__ qo,
    unsigned short* __restrict__ ko, unsigned short* __restrict__ vo) {
  int wid = (blockIdx.x * 256 + threadIdx.x) >> 6;
  int lane = threadIdx.x & 63;
  int row = wid >> 4;   // 0..4095 (= b*2048 + s)
  int unit = wid & 15;  // 0..7 q heads, 8..11 k heads, 12..15 v heads
  int b = row >> 11, s = row & 2047;
  int d0 = lane * 4;
  const unsigned short* x = qkv + (size_t)row * NQKV + unit * HD_N + d0;
  u16x4 xb = *(const u16x4*)x;
  float v[4];
#pragma unroll
  for (int j = 0; j < 4; j++) v[j] = bf2f(xb[j]);
  float ss = v[0] * v[0] + v[1] * v[1] + v[2] * v[2] + v[3] * v[3];
#pragma unroll
  for (int off = 32; off >= 1; off >>= 1) ss += __shfl_xor(ss, off);
  float inv = 1.0f / sqrtf(ss * (1.0f / 256.0f) + 1e-6f);

  int kb = s >> 5;
  if (unit >= 12) {  // v: norm only, tiled+swizzled
    int hv = unit - 12;
    int ks = s & 31;
    unsigned short* slab = vo + ((size_t)(b * HKV_N + hv) * 64 + kb) * 8192;
#pragma unroll
    for (int j = 0; j < 4; j++) {
      int d = d0 + j;
      int pos = d * 32 + (((ks >> 3) ^ ((d >> 1) & 3)) << 3) + (ks & 7);
      slab[pos] = f2bf(v[j] * inv);
    }
    return;
  }
  const float* wv = (unit < 8) ? qw : kw;
  const float qsc = (unit < 8) ? SC2 : 1.0f;  // fold softmax scale into Q
  f32x4 wl = *(const f32x4*)(wv + d0);
  float y[4];
#pragma unroll
  for (int j = 0; j < 4; j++) y[j] = v[j] * inv * wl[j] * qsc;
  float yp[4];
#pragma unroll
  for (int j = 0; j < 4; j++) yp[j] = __shfl_xor(y[j], 32);  // element at d ^ 128
  // batch-0, d<128 slice (cos[d] == cos[d&127]; broadcast over batch)
  f32x4 cv = *(const f32x4*)(cosb + (size_t)s * HD_N + (d0 & 127));
  f32x4 sv = *(const f32x4*)(sinb + (size_t)s * HD_N + (d0 & 127));
  u16x4 out;
#pragma unroll
  for (int j = 0; j < 4; j++) {
    float rot = (d0 < 128) ? -yp[j] : yp[j];
    out[j] = f2bf(y[j] * cv[j] + rot * sv[j]);
  }
  if (unit < 8) {
    unsigned short* dst = qo + ((size_t)(b * HQ_N + unit) * S_LEN + s) * HD_N + d0;
    *(u16x4*)dst = out;
  } else {
    int kv = unit - 8;
    int kr = s & 31;
    unsigned short* dst = ko + ((size_t)(b * HKV_N + kv) * 64 + kb) * 8192 + kr * 256 +
                          (((d0 >> 3) ^ (kr & 7)) << 3) + (d0 & 7);
    *(u16x4*)dst = out;
  }
}

// ---------------- flash attention: GQA-paired 4-wave blocks, QBLK=32, KVBLK=32 ---------
__global__ __launch_bounds__(256) void attn_kernel(const unsigned short* __restrict__ qb,
                                                   const unsigned short* __restrict__ kb_,
                                                   const unsigned short* __restrict__ vb_,
                                                   unsigned short* __restrict__ attn) {
  __shared__ unsigned short kt[2][8192];
  __shared__ unsigned short vt[2][8192];
  const int lane = threadIdx.x & 63;
  const int w = threadIdx.x >> 6;   // 0..3
  const int r = lane & 15, g = lane >> 4;
  const int pblk = blockIdx.x;
  const int lb = (pblk & 7) * 64 + (pblk >> 3);  // XCD chunk = 64 blocks = one (b,kvh)
  const int qt = lb & 63;
  const int kvh = (lb >> 6) & 3;
  const int b = lb >> 8;
  const int h = kvh * 2 + (w >> 1);  // wave's head within the GQA pair
  const int ww = w & 1;              // wave-in-head (16-row group)
  const int q0 = qt * 32;
  const int qi = q0 + ww * 16 + r;   // this lane's q-row
  const int wqmin = q0 + ww * 16, wqmax = wqmin + 15;
  const unsigned short* qbase = qb + ((size_t)(b * HQ_N + h) * S_LEN + q0 + ww * 16) * HD_N;
  const unsigned short* kslabs = kb_ + (size_t)(b * HKV_N + kvh) * S_LEN * HD_N;
  const unsigned short* vslabs = vb_ + (size_t)(b * HKV_N + kvh) * S_LEN * HD_N;

  bf16x8 qf[8];
#pragma unroll
  for (int c = 0; c < 8; c++)
    qf[c] = *(const bf16x8*)(qbase + (size_t)r * HD_N + c * 32 + g * 8);

  f32x4 o[16];
#pragma unroll
  for (int i = 0; i < 16; i++) o[i] = (f32x4){0.f, 0.f, 0.f, 0.f};
  float m = -1e30f, lsum = 0.0f;

  int lo = q0 - 1023; if (lo < 0) lo = 0; lo &= ~31;
  const int hiend = q0 + 32;

  {
    const unsigned short* ks = kslabs + (size_t)(lo >> 5) * 8192;
    const unsigned short* vs = vslabs + (size_t)(lo >> 5) * 8192;
#pragma unroll
    for (int j = 0; j < 4; j++) {
      GLDS16(ks + j * 2048 + w * 512 + lane * 8, &kt[0][j * 2048 + w * 512]);
      GLDS16(vs + j * 2048 + w * 512 + lane * 8, &vt[0][j * 2048 + w * 512]);
    }
  }
  __syncthreads();

  int cur = 0;
  for (int key0 = lo; key0 < hiend; key0 += 32) {
    if (key0 + 32 < hiend) {
      const unsigned short* ks = kslabs + (size_t)((key0 >> 5) + 1) * 8192;
      const unsigned short* vs = vslabs + (size_t)((key0 >> 5) + 1) * 8192;
#pragma unroll
      for (int j = 0; j < 4; j++) {
        GLDS16(ks + j * 2048 + w * 512 + lane * 8, &kt[cur ^ 1][j * 2048 + w * 512]);
        GLDS16(vs + j * 2048 + w * 512 + lane * 8, &vt[cur ^ 1][j * 2048 + w * 512]);
      }
    }
    if (key0 <= wqmax && key0 + 31 >= wqmin - 1023) {
      const unsigned short* kc = kt[cur];
      const unsigned short* vc = vt[cur];

      f32x4 st0 = (f32x4){0.f, 0.f, 0.f, 0.f}, st1 = (f32x4){0.f, 0.f, 0.f, 0.f};
      __builtin_amdgcn_s_setprio(1);
#pragma unroll
      for (int c = 0; c < 8; c++) {
        int x0 = (((c * 4 + g) ^ (r & 7)) << 3);
        bf16x8 kf0 = *(const bf16x8*)(kc + r * 256 + x0);
        bf16x8 kf1 = *(const bf16x8*)(kc + (16 + r) * 256 + x0);
        st0 = __builtin_amdgcn_mfma_f32_16x16x32_bf16(kf0, qf[c], st0, 0, 0, 0);
        st1 = __builtin_amdgcn_mfma_f32_16x16x32_bf16(kf1, qf[c], st1, 0, 0, 0);
      }
      __builtin_amdgcn_s_setprio(0);
      float p[2][4];
      float pm = -3e30f;
#pragma unroll
      for (int t = 0; t < 2; t++)
#pragma unroll
        for (int e = 0; e < 4; e++) {
          int key = key0 + t * 16 + 4 * g + e;
          float sv = (t == 0 ? st0[e] : st1[e]);
          sv = (key <= qi && key > qi - 1024) ? sv : -2e30f;
          p[t][e] = sv;
          pm = fmaxf(pm, sv);
        }
      pm = fmaxf(pm, __shfl_xor(pm, 16));
      pm = fmaxf(pm, __shfl_xor(pm, 32));
      if (!__all(pm <= m + 8.0f)) {
        float newm = fmaxf(m, pm);
        float f = exp2f(m - newm);
        m = newm;
        lsum *= f;
#pragma unroll
        for (int i = 0; i < 16; i++) {
          o[i][0] *= f; o[i][1] *= f; o[i][2] *= f; o[i][3] *= f;
        }
      }
      float ps = 0.0f;
#pragma unroll
      for (int t = 0; t < 2; t++)
#pragma unroll
        for (int e = 0; e < 4; e++) {
          float pe = exp2f(p[t][e] - m);
          p[t][e] = pe;
          ps += pe;
        }
      ps += __shfl_xor(ps, 16);
      ps += __shfl_xor(ps, 32);
      lsum += ps;
      short pk[8];
#pragma unroll
      for (int e2 = 0; e2 < 8; e2++) {
        int srcl = r + 16 * (2 * (g & 1) + (e2 >> 2));
        float a0 = __shfl(p[0][e2 & 3], srcl);
        float a1 = __shfl(p[1][e2 & 3], srcl);
        pk[e2] = (short)f2bf((g < 2) ? a0 : a1);
      }
      bf16x8 pf = {pk[0], pk[1], pk[2], pk[3], pk[4], pk[5], pk[6], pk[7]};
      int yx = ((g ^ ((r >> 1) & 3)) << 3);
      __builtin_amdgcn_s_setprio(1);
#pragma unroll
      for (int c2 = 0; c2 < 16; c2++) {
        bf16x8 vf = *(const bf16x8*)(vc + (c2 * 16 + r) * 32 + yx);
        o[c2] = __builtin_amdgcn_mfma_f32_16x16x32_bf16(vf, pf, o[c2], 0, 0, 0);
      }
      __builtin_amdgcn_s_setprio(0);
    }
    __syncthreads();
    cur ^= 1;
  }
  float linv = 1.0f / lsum;
  unsigned short* arow = attn + ((size_t)(b * S_LEN) + q0 + ww * 16 + r) * (HQ_N * HD_N) + h * HD_N;
#pragma unroll
  for (int c2 = 0; c2 < 16; c2++) {
    unsigned int w0 = (unsigned)f2bf(o[c2][0] * linv) | ((unsigned)f2bf(o[c2][1] * linv) << 16);
    unsigned int w1 = (unsigned)f2bf(o[c2][2] * linv) | ((unsigned)f2bf(o[c2][3] * linv) << 16);
    *(unsigned int*)(arow + c2 * 16 + 4 * g) = w0;
    *(unsigned int*)(arow + c2 * 16 + 4 * g + 2) = w1;
  }
}

extern "C" void kernel_launch(void* const* d_in, const int* in_sizes, int n_in,
                              void* d_out, int out_size, void* d_ws, size_t ws_size,
                              hipStream_t stream) {
  const float* hid  = (const float*)d_in[0];
  const float* cosb = (const float*)d_in[1];
  const float* sinb = (const float*)d_in[2];
  const float* Wq   = (const float*)d_in[4];
  const float* Wk   = (const float*)d_in[5];
  const float* Wv   = (const float*)d_in[6];
  const float* Wo   = (const float*)d_in[7];
  const float* qw   = (const float*)d_in[8];
  const float* kw   = (const float*)d_in[9];

  char* ws = (char*)d_ws;
  unsigned short* Xbf   = (unsigned short*)(ws + 0);            // 4096x2560 bf16
  unsigned short* Wcat  = (unsigned short*)(ws + 20971520);     // 4096x2560 bf16
  unsigned short* Wob   = (unsigned short*)(ws + 41943040);     // 2560x2048 bf16
  unsigned short* QKV   = (unsigned short*)(ws + 52428800);     // 4096x4096 bf16
  unsigned short* qbuf  = (unsigned short*)(ws + 85983232);     // 2*8*2048*256
  unsigned short* kbuf  = (unsigned short*)(ws + 102760448);    // 2*4*2048*256 (tiled)
  unsigned short* vbuf  = (unsigned short*)(ws + 111149056);    // 2*4*2048*256 (tiled)
  unsigned short* attnb = (unsigned short*)(ws + 119537664);    // 4096x2048 bf16
  // total: 136,314,880 B

  // 1) merged casts (one launch)
  cvt_all_kernel<<<25600, 256, 0, stream>>>(hid, Wq, Wk, Wv, Wo, Xbf, Wcat, Wob);
  // 2) QKV projection: QKV = X @ Wcat^T (bf16 out, 256 blocks)
  gemm8p<1><<<256, 512, 0, stream>>>(Xbf, Wcat, QKV, 4096, 4096, 2560, 16);
  // 3) RMSNorm + RoPE (standalone, 16384 blocks — full occupancy, BW-bound)
  rms_rope_kernel<<<16384, 256, 0, stream>>>(QKV, cosb, sinb, qw, kw, qbuf, kbuf, vbuf);
  // 4) sliding-window flash attention (GQA-paired, 512 blocks x 256 thr, 2 blocks/CU)
  attn_kernel<<<512, 256, 0, stream>>>(qbuf, kbuf, vbuf, attnb);
  // 5) output projection: d_out = attn @ Wo^T (fp32 out, 160 blocks)
  gemm8p<0><<<160, 512, 0, stream>>>(attnb, Wob, (float*)d_out, 4096, 2560, 2048, 10);
}

// Round 13
// 224.178 us; speedup vs baseline: 1.3252x; 1.3252x over previous
//
#include <hip/hip_runtime.h>

#define S_LEN 2048
#define HIDN  2560
#define HQ_N  8
#define HKV_N 4
#define HD_N  256
#define NQKV  4096   // HQ*HD + 2*HKV*HD
#define MROWS 4096   // B*S
#define SC2   0.09016844005556021f  // HD^-0.5 * log2(e), folded into Q at producer

typedef __attribute__((ext_vector_type(8))) short bf16x8;
typedef __attribute__((ext_vector_type(4))) float f32x4;
typedef __attribute__((ext_vector_type(4))) unsigned short u16x4;
typedef __attribute__((ext_vector_type(8))) unsigned short u16x8;

typedef const __attribute__((address_space(1))) unsigned int* gas_t;
typedef __attribute__((address_space(3))) unsigned int* las_t;
#define GLDS16(gp, lp) __builtin_amdgcn_global_load_lds((gas_t)(const void*)(gp), \
                                                        (las_t)(void*)(lp), 16, 0, 0)

static __device__ __forceinline__ float bf2f(unsigned short u) {
  unsigned int x = ((unsigned int)u) << 16;
  return __builtin_bit_cast(float, x);
}
static __device__ __forceinline__ unsigned short f2bf(float f) {
  unsigned int u = __builtin_bit_cast(unsigned int, f);
  u += 0x7fffu + ((u >> 16) & 1u);
  return (unsigned short)(u >> 16);
}

// ---------------- merged fp32 -> bf16 cast for all 5 tensors (one launch) ----------------
__global__ void cvt_all_kernel(const float* __restrict__ hid, const float* __restrict__ Wq,
                               const float* __restrict__ Wk, const float* __restrict__ Wv,
                               const float* __restrict__ Wo, unsigned short* __restrict__ Xbf,
                               unsigned short* __restrict__ Wcat,
                               unsigned short* __restrict__ Wob) {
  int i = blockIdx.x * 256 + threadIdx.x;
  const float* src;
  unsigned short* dst;
  int j;
  if (i < 2621440) { src = hid; dst = Xbf; j = i; }
  else if (i < 3932160) { src = Wq; dst = Wcat; j = i - 2621440; }
  else if (i < 4587520) { src = Wk; dst = Wcat + 5242880; j = i - 3932160; }
  else if (i < 5242880) { src = Wv; dst = Wcat + 7864320; j = i - 4587520; }
  else { src = Wo; dst = Wob; j = i - 5242880; }
  f32x4 v = ((const f32x4*)src)[j];
  u16x4 o;
  o[0] = f2bf(v[0]); o[1] = f2bf(v[1]); o[2] = f2bf(v[2]); o[3] = f2bf(v[3]);
  ((u16x4*)dst)[j] = o;
}

// ---------------- 256x256-tile pipelined GEMM, 4-phase/K-tile (R7 proven loop) ----------
// EPI=0: plain fp32 C store (out-proj). EPI=1: QKV projection with FUSED RMSNorm+RoPE
// epilogue — each 256-col tile is exactly one head unit (bx): 0-7 q, 8-11 k, 12-15 v.
template <int EPI>
__global__ __launch_bounds__(512, 2) void gemm8p(const unsigned short* __restrict__ A,
                                                 const unsigned short* __restrict__ B,
                                                 void* __restrict__ C,
                                                 int M, int N, int K, int gx,
                                                 const float* __restrict__ cosb,
                                                 const float* __restrict__ sinb,
                                                 const float* __restrict__ qw,
                                                 const float* __restrict__ kw,
                                                 unsigned short* __restrict__ qo,
                                                 unsigned short* __restrict__ ko,
                                                 unsigned short* __restrict__ vo) {
  __shared__ unsigned short ldsw[65536];  // 2 bufs x 32768 elems (128 KB)
  const int tid = threadIdx.x;
  const int lane = tid & 63;
  const int w = tid >> 6;
  const int r = lane & 15, g = lane >> 4;
  const int wr = w >> 2, wc = w & 3;
  const int NT = K >> 6;

  const int nwg = gridDim.x;
  const int cpx = nwg >> 3;
  const int bid = blockIdx.x;
  const int sbid = (bid & 7) * cpx + (bid >> 3);
  const int bx = sbid % gx, by = sbid / gx;
  const int brow = by * 256, bcol = bx * 256;

  const int lr = lane >> 3;
  const int lc8 = ((lane & 7) ^ lr) * 8;
  const unsigned short* gA = A + (size_t)(brow + w * 16 + lr) * K + lc8;
  const unsigned short* gB = B + (size_t)(bcol + w * 16 + lr) * K + lc8;
  const size_t rK8 = (size_t)8 * K;
  const size_t rK128 = (size_t)128 * K;
  const int wl = w * 1024;

  const int sl0 = (((g ^ (r & 3)) + 4 * ((r >> 2) & 1))) * 8;
  int aoff[8], boff[4];
#pragma unroll
  for (int mf = 0; mf < 8; mf++) aoff[mf] = wr * 8192 + (mf * 16 + r) * 64 + sl0;
#pragma unroll
  for (int nf = 0; nf < 4; nf++)
    boff[nf] = 16384 + (wc >> 1) * 8192 + ((wc & 1) * 64 + nf * 16 + r) * 64 + sl0;

  f32x4 acc[8][4];
#pragma unroll
  for (int i = 0; i < 8; i++)
#pragma unroll
    for (int j = 0; j < 4; j++) acc[i][j] = (f32x4){0.f, 0.f, 0.f, 0.f};

  {
    unsigned short* b0 = ldsw;
    unsigned short* b1 = ldsw + 32768;
    GLDS16(gA, b0 + wl);                    GLDS16(gA + rK8, b0 + wl + 512);
    GLDS16(gA + rK128, b0 + 8192 + wl);     GLDS16(gA + rK128 + rK8, b0 + 8192 + wl + 512);
    GLDS16(gB, b0 + 16384 + wl);            GLDS16(gB + rK8, b0 + 16384 + wl + 512);
    GLDS16(gB + rK128, b0 + 24576 + wl);    GLDS16(gB + rK128 + rK8, b0 + 24576 + wl + 512);
    GLDS16(gA + 64, b1 + wl);               GLDS16(gA + 64 + rK8, b1 + wl + 512);
    GLDS16(gA + 64 + rK128, b1 + 8192 + wl); GLDS16(gA + 64 + rK128 + rK8, b1 + 8192 + wl + 512);
  }
  asm volatile("s_waitcnt vmcnt(4)" ::: "memory");
  __builtin_amdgcn_sched_barrier(0);
  __builtin_amdgcn_s_barrier();

  for (int u = 0; u < NT; ++u) {
    const unsigned short* cbp = ldsw + (u & 1) * 32768;
    unsigned short* cbw = ldsw + (u & 1) * 32768;
    unsigned short* obw = ldsw + ((u & 1) ^ 1) * 32768;
    const int c1 = (u + 1) * 64;
    const int c2 = (u + 2) * 64;
    const bool s1 = (u + 1) < NT, s2 = (u + 2) < NT;

    bf16x8 af0[4], bk0[4], af1[4];
#pragma unroll
    for (int mf = 0; mf < 4; mf++) af0[mf] = *(const bf16x8*)(cbp + aoff[mf]);
#pragma unroll
    for (int nf = 0; nf < 4; nf++) bk0[nf] = *(const bf16x8*)(cbp + boff[nf]);
#pragma unroll
    for (int mf = 0; mf < 4; mf++) af1[mf] = *(const bf16x8*)(cbp + aoff[4 + mf]);
    if (s1) {
      GLDS16(gB + c1, obw + 16384 + wl);
      GLDS16(gB + c1 + rK8, obw + 16384 + wl + 512);
    }
    __builtin_amdgcn_s_setprio(1);
#pragma unroll
    for (int mf = 0; mf < 4; mf++)
#pragma unroll
      for (int nf = 0; nf < 4; nf++)
        acc[mf][nf] = __builtin_amdgcn_mfma_f32_16x16x32_bf16(af0[mf], bk0[nf], acc[mf][nf], 0, 0, 0);
    __builtin_amdgcn_s_setprio(0);

    bf16x8 ag0[4], ag1[4];
#pragma unroll
    for (int mf = 0; mf < 4; mf++) ag0[mf] = *(const bf16x8*)(cbp + (aoff[mf] ^ 32));
#pragma unroll
    for (int mf = 0; mf < 4; mf++) ag1[mf] = *(const bf16x8*)(cbp + (aoff[4 + mf] ^ 32));
    if (s1) {
      GLDS16(gB + c1 + rK128, obw + 24576 + wl);
      GLDS16(gB + c1 + rK128 + rK8, obw + 24576 + wl + 512);
    }
    __builtin_amdgcn_s_setprio(1);
#pragma unroll
    for (int mf = 0; mf < 4; mf++)
#pragma unroll
      for (int nf = 0; nf < 4; nf++)
        acc[4 + mf][nf] = __builtin_amdgcn_mfma_f32_16x16x32_bf16(af1[mf], bk0[nf], acc[4 + mf][nf], 0, 0, 0);
    __builtin_amdgcn_s_setprio(0);
    asm volatile("s_waitcnt lgkmcnt(0)" ::: "memory");
    __builtin_amdgcn_sched_barrier(0);
    __builtin_amdgcn_s_barrier();

    bf16x8 bk1[4];
#pragma unroll
    for (int nf = 0; nf < 4; nf++) bk1[nf] = *(const bf16x8*)(cbp + (boff[nf] ^ 32));
    if (s2) {
      GLDS16(gA + c2, cbw + wl);
      GLDS16(gA + c2 + rK8, cbw + wl + 512);
    }
    __builtin_amdgcn_s_setprio(1);
#pragma unroll
    for (int mf = 0; mf < 4; mf++)
#pragma unroll
      for (int nf = 0; nf < 4; nf++)
        acc[mf][nf] = __builtin_amdgcn_mfma_f32_16x16x32_bf16(ag0[mf], bk1[nf], acc[mf][nf], 0, 0, 0);
    __builtin_amdgcn_s_setprio(0);

    if (s2) {
      GLDS16(gA + c2 + rK128, cbw + 8192 + wl);
      GLDS16(gA + c2 + rK128 + rK8, cbw + 8192 + wl + 512);
    }
    __builtin_amdgcn_s_setprio(1);
#pragma unroll
    for (int mf = 0; mf < 4; mf++)
#pragma unroll
      for (int nf = 0; nf < 4; nf++)
        acc[4 + mf][nf] = __builtin_amdgcn_mfma_f32_16x16x32_bf16(ag1[mf], bk1[nf], acc[4 + mf][nf], 0, 0, 0);
    __builtin_amdgcn_s_setprio(0);
    if (s2) { asm volatile("s_waitcnt vmcnt(4)" ::: "memory"); }
    else    { asm volatile("s_waitcnt vmcnt(0)" ::: "memory"); }
    __builtin_amdgcn_sched_barrier(0);
    __builtin_amdgcn_s_barrier();
  }

  if (EPI == 0) {
#pragma unroll
    for (int i = 0; i < 8; i++)
#pragma unroll
      for (int j = 0; j < 4; j++) {
        const int col = bcol + wc * 64 + j * 16 + r;
        const int rowb = brow + wr * 128 + i * 16 + g * 4;
#pragma unroll
        for (int e = 0; e < 4; e++)
          ((float*)C)[(size_t)(rowb + e) * N + col] = acc[i][j][e];
      }
  } else {
    // -------- fused RMSNorm + RoPE epilogue; this tile = unit bx --------
    const int unit = bx;
    const int bq = by >> 3;
    const int sbase = (by & 7) * 256;
    float* ldsf = (float*)ldsw;
    // 1) per-row partial sum of squares -> ldsf[row][wc]
#pragma unroll
    for (int i = 0; i < 8; i++)
#pragma unroll
      for (int e = 0; e < 4; e++) {
        float ps = 0.f;
#pragma unroll
        for (int j = 0; j < 4; j++) { float v = acc[i][j][e]; ps += v * v; }
        ps += __shfl_xor(ps, 1); ps += __shfl_xor(ps, 2);
        ps += __shfl_xor(ps, 4); ps += __shfl_xor(ps, 8);
        if (r == 0) ldsf[(wr * 128 + i * 16 + g * 4 + e) * 4 + wc] = ps;
      }
    __syncthreads();
    // 2) inv rms per (i,e) row
    float inv[8][4];
#pragma unroll
    for (int i = 0; i < 8; i++)
#pragma unroll
      for (int e = 0; e < 4; e++) {
        int rl = wr * 128 + i * 16 + g * 4 + e;
        f32x4 p4 = *(const f32x4*)&ldsf[rl * 4];
        inv[i][e] = rsqrtf((p4[0] + p4[1] + p4[2] + p4[3]) * (1.0f / 256.0f) + 1e-6f);
      }
    if (unit >= 12) {
      // v: DIRECT u16x4 stores from acc into tiled+swizzled slab (line-dense).
      const int hv = unit - 12;
      unsigned short* vbase = vo + (size_t)(bq * HKV_N + hv) * 64 * 8192;
      const int rsw = (r >> 1) & 3;
#pragma unroll
      for (int i = 0; i < 8; i++) {
        const int slabi = (sbase >> 5) + wr * 4 + (i >> 1);
        unsigned short* slab = vbase + (size_t)slabi * 8192;
        const int sIdx = (i & 1) * 2 + (g >> 1);
        const int soff = ((sIdx ^ rsw) << 3) + (g & 1) * 4;
#pragma unroll
        for (int j = 0; j < 4; j++) {
          const int d = wc * 64 + j * 16 + r;
          u16x4 ov;
#pragma unroll
          for (int e = 0; e < 4; e++) ov[e] = f2bf(acc[i][j][e] * inv[i][e]);
          *(u16x4*)(slab + d * 32 + soff) = ov;
        }
      }
    } else {
      // q/k: normalized+weighted y -> LDS plane (8-group XOR swizzle), then
      // coalesced rope pass: 16 lanes/row x 4 rows/wave, 256 B runs.
      // RoPE symmetry: cos[d]==cos[d&127], batch-broadcast -> batch-0 d<128 slice.
      const float* wvec = (unit < 8) ? qw : kw;
      const float qsc = (unit < 8) ? SC2 : 1.0f;
      float wj[4];
#pragma unroll
      for (int j = 0; j < 4; j++) wj[j] = wvec[wc * 64 + j * 16 + r] * qsc;
      __syncthreads();  // ldsf reads done before plane overwrites
#pragma unroll
      for (int i = 0; i < 8; i++)
#pragma unroll
        for (int e = 0; e < 4; e++) {
          int rl = wr * 128 + i * 16 + g * 4 + e;
          int sw = (rl & 7) << 3;
          float iv = inv[i][e];
#pragma unroll
          for (int j = 0; j < 4; j++) {
            int d = wc * 64 + j * 16 + r;
            ldsw[rl * 256 + (d ^ sw)] = f2bf(acc[i][j][e] * iv * wj[j]);
          }
        }
      __syncthreads();
      const int lr16 = lane & 15;
      const int row4 = lane >> 4;
      const int dlo = lr16 * 8, dhi = dlo + 128;
      unsigned short* qdst0 = nullptr;
      unsigned short* kbase2 = nullptr;
      if (unit < 8) qdst0 = qo + (size_t)(bq * HQ_N + unit) * S_LEN * HD_N;
      else kbase2 = ko + (size_t)(bq * HKV_N + (unit - 8)) * 64 * 8192;
#pragma unroll
      for (int it = 0; it < 8; it++) {
        const int rl2 = w * 32 + it * 4 + row4;
        const int s2 = sbase + rl2;
        const int sw2 = (rl2 & 7) << 3;
        bf16x8 ylo = *(const bf16x8*)(ldsw + rl2 * 256 + (dlo ^ sw2));
        bf16x8 yhi = *(const bf16x8*)(ldsw + rl2 * 256 + (dhi ^ sw2));
        const float* cp = cosb + (size_t)s2 * HD_N;  // batch-0 slice; d<128 only
        const float* sp = sinb + (size_t)s2 * HD_N;
        f32x4 cA = *(const f32x4*)(cp + dlo), cB = *(const f32x4*)(cp + dlo + 4);
        f32x4 sA = *(const f32x4*)(sp + dlo), sB = *(const f32x4*)(sp + dlo + 4);
        u16x8 olo, ohi;
#pragma unroll
        for (int t = 0; t < 8; t++) {
          float a  = bf2f((unsigned short)ylo[t]);
          float b2 = bf2f((unsigned short)yhi[t]);
          float cl = (t < 4) ? cA[t] : cB[t - 4];
          float slv = (t < 4) ? sA[t] : sB[t - 4];
          olo[t] = f2bf(a * cl - b2 * slv);
          ohi[t] = f2bf(b2 * cl + a * slv);  // cos/sin identical for d and d+128
        }
        if (unit < 8) {
          unsigned short* qd = qdst0 + (size_t)s2 * HD_N;
          *(u16x8*)(qd + dlo) = olo;
          *(u16x8*)(qd + dhi) = ohi;
        } else {
          const int kr = s2 & 31;
          unsigned short* kd = kbase2 + (size_t)(s2 >> 5) * 8192 + kr * 256;
          const int sl_ = (lr16 ^ (kr & 7)) << 3;
          *(u16x8*)(kd + sl_) = olo;
          *(u16x8*)(kd + 128 + sl_) = ohi;
        }
      }
    }
  }
}

// ---------------- flash attention: GQA-paired 8-wave blocks, QBLK=64, KVBLK=64 ---------
// Block = both heads of one kvh group x 4 waves x 16 q-rows. K/V staged ONCE for 2 heads.
// LDS 128 KB double-buffered (1 block/CU, 8 waves). XCD chunk (32 blocks) = one (b,kvh).
__global__ __launch_bounds__(512) void attn_kernel(const unsigned short* __restrict__ qb,
                                                   const unsigned short* __restrict__ kb_,
                                                   const unsigned short* __restrict__ vb_,
                                                   unsigned short* __restrict__ attn) {
  __shared__ unsigned short kt[2][16384];
  __shared__ unsigned short vt[2][16384];
  const int lane = threadIdx.x & 63;
  const int w = threadIdx.x >> 6;   // 0..7
  const int r = lane & 15, g = lane >> 4;
  const int pblk = blockIdx.x;
  const int lb = (pblk & 7) * 32 + (pblk >> 3);  // XCD chunk = 32 blocks = one (b,kvh)
  const int qt = lb & 31;
  const int kvh = (lb >> 5) & 3;
  const int b = lb >> 7;
  const int h = kvh * 2 + (w >> 2);  // wave's head within the GQA pair
  const int ww = w & 3;              // wave-in-head
  const int q0 = qt * 64;
  const int qi = q0 + ww * 16 + r;   // this lane's q-row
  const int wqmin = q0 + ww * 16, wqmax = wqmin + 15;
  const unsigned short* qbase = qb + ((size_t)(b * HQ_N + h) * S_LEN + q0 + ww * 16) * HD_N;
  const unsigned short* kslabs = kb_ + (size_t)(b * HKV_N + kvh) * S_LEN * HD_N;
  const unsigned short* vslabs = vb_ + (size_t)(b * HKV_N + kvh) * S_LEN * HD_N;

  bf16x8 qf[8];
#pragma unroll
  for (int c = 0; c < 8; c++)
    qf[c] = *(const bf16x8*)(qbase + (size_t)r * HD_N + c * 32 + g * 8);

  f32x4 o[16];
#pragma unroll
  for (int i = 0; i < 16; i++) o[i] = (f32x4){0.f, 0.f, 0.f, 0.f};
  float m = -1e30f, lsum = 0.0f;

  int lo = q0 - 1023; if (lo < 0) lo = 0; lo &= ~63;
  const int hiend = q0 + 64;

  {
    const unsigned short* ks = kslabs + (size_t)(lo >> 6) * 16384;
    const unsigned short* vs = vslabs + (size_t)(lo >> 6) * 16384;
#pragma unroll
    for (int j = 0; j < 4; j++) {
      GLDS16(ks + j * 4096 + w * 512 + lane * 8, &kt[0][j * 4096 + w * 512]);
      GLDS16(vs + j * 4096 + w * 512 + lane * 8, &vt[0][j * 4096 + w * 512]);
    }
  }
  __syncthreads();

  int cur = 0;
  for (int kk = lo; kk < hiend; kk += 64) {
    if (kk + 64 < hiend) {
      const unsigned short* ks = kslabs + (size_t)((kk >> 6) + 1) * 16384;
      const unsigned short* vs = vslabs + (size_t)((kk >> 6) + 1) * 16384;
#pragma unroll
      for (int j = 0; j < 4; j++) {
        GLDS16(ks + j * 4096 + w * 512 + lane * 8, &kt[cur ^ 1][j * 4096 + w * 512]);
        GLDS16(vs + j * 4096 + w * 512 + lane * 8, &vt[cur ^ 1][j * 4096 + w * 512]);
      }
    }
#pragma unroll
    for (int s = 0; s < 2; s++) {
      const int key0 = kk + s * 32;
      if (key0 <= wqmax && key0 + 31 >= wqmin - 1023) {
        const unsigned short* kc = &kt[cur][s * 8192];
        const unsigned short* vc = &vt[cur][s * 8192];

        f32x4 st0 = (f32x4){0.f, 0.f, 0.f, 0.f}, st1 = (f32x4){0.f, 0.f, 0.f, 0.f};
        __builtin_amdgcn_s_setprio(1);
#pragma unroll
        for (int c = 0; c < 8; c++) {
          int x0 = (((c * 4 + g) ^ (r & 7)) << 3);
          bf16x8 kf0 = *(const bf16x8*)(kc + r * 256 + x0);
          bf16x8 kf1 = *(const bf16x8*)(kc + (16 + r) * 256 + x0);
          st0 = __builtin_amdgcn_mfma_f32_16x16x32_bf16(kf0, qf[c], st0, 0, 0, 0);
          st1 = __builtin_amdgcn_mfma_f32_16x16x32_bf16(kf1, qf[c], st1, 0, 0, 0);
        }
        __builtin_amdgcn_s_setprio(0);
        float p[2][4];
        float pm = -3e30f;
#pragma unroll
        for (int t = 0; t < 2; t++)
#pragma unroll
          for (int e = 0; e < 4; e++) {
            int key = key0 + t * 16 + 4 * g + e;
            float sv = (t == 0 ? st0[e] : st1[e]);
            sv = (key <= qi && key > qi - 1024) ? sv : -2e30f;
            p[t][e] = sv;
            pm = fmaxf(pm, sv);
          }
        pm = fmaxf(pm, __shfl_xor(pm, 16));
        pm = fmaxf(pm, __shfl_xor(pm, 32));
        if (!__all(pm <= m + 8.0f)) {
          float newm = fmaxf(m, pm);
          float f = exp2f(m - newm);
          m = newm;
          lsum *= f;
#pragma unroll
          for (int i = 0; i < 16; i++) {
            o[i][0] *= f; o[i][1] *= f; o[i][2] *= f; o[i][3] *= f;
          }
        }
        float ps = 0.0f;
#pragma unroll
        for (int t = 0; t < 2; t++)
#pragma unroll
          for (int e = 0; e < 4; e++) {
            float pe = exp2f(p[t][e] - m);
            p[t][e] = pe;
            ps += pe;
          }
        ps += __shfl_xor(ps, 16);
        ps += __shfl_xor(ps, 32);
        lsum += ps;
        short pk[8];
#pragma unroll
        for (int e2 = 0; e2 < 8; e2++) {
          int srcl = r + 16 * (2 * (g & 1) + (e2 >> 2));
          float a0 = __shfl(p[0][e2 & 3], srcl);
          float a1 = __shfl(p[1][e2 & 3], srcl);
          pk[e2] = (short)f2bf((g < 2) ? a0 : a1);
        }
        bf16x8 pf = {pk[0], pk[1], pk[2], pk[3], pk[4], pk[5], pk[6], pk[7]};
        int yx = ((g ^ ((r >> 1) & 3)) << 3);
        __builtin_amdgcn_s_setprio(1);
#pragma unroll
        for (int c2 = 0; c2 < 16; c2++) {
          bf16x8 vf = *(const bf16x8*)(vc + (c2 * 16 + r) * 32 + yx);
          o[c2] = __builtin_amdgcn_mfma_f32_16x16x32_bf16(vf, pf, o[c2], 0, 0, 0);
        }
        __builtin_amdgcn_s_setprio(0);
      }
    }
    __syncthreads();
    cur ^= 1;
  }
  float linv = 1.0f / lsum;
  unsigned short* arow = attn + ((size_t)(b * S_LEN) + q0 + ww * 16 + r) * (HQ_N * HD_N) + h * HD_N;
#pragma unroll
  for (int c2 = 0; c2 < 16; c2++) {
    unsigned int w0 = (unsigned)f2bf(o[c2][0] * linv) | ((unsigned)f2bf(o[c2][1] * linv) << 16);
    unsigned int w1 = (unsigned)f2bf(o[c2][2] * linv) | ((unsigned)f2bf(o[c2][3] * linv) << 16);
    *(unsigned int*)(arow + c2 * 16 + 4 * g) = w0;
    *(unsigned int*)(arow + c2 * 16 + 4 * g + 2) = w1;
  }
}

extern "C" void kernel_launch(void* const* d_in, const int* in_sizes, int n_in,
                              void* d_out, int out_size, void* d_ws, size_t ws_size,
                              hipStream_t stream) {
  const float* hid  = (const float*)d_in[0];
  const float* cosb = (const float*)d_in[1];
  const float* sinb = (const float*)d_in[2];
  const float* Wq   = (const float*)d_in[4];
  const float* Wk   = (const float*)d_in[5];
  const float* Wv   = (const float*)d_in[6];
  const float* Wo   = (const float*)d_in[7];
  const float* qw   = (const float*)d_in[8];
  const float* kw   = (const float*)d_in[9];

  char* ws = (char*)d_ws;
  unsigned short* Xbf   = (unsigned short*)(ws + 0);            // 4096x2560 bf16
  unsigned short* Wcat  = (unsigned short*)(ws + 20971520);     // 4096x2560 bf16
  unsigned short* Wob   = (unsigned short*)(ws + 41943040);     // 2560x2048 bf16
  unsigned short* qbuf  = (unsigned short*)(ws + 85983232);     // 2*8*2048*256
  unsigned short* kbuf  = (unsigned short*)(ws + 102760448);    // 2*4*2048*256 (tiled)
  unsigned short* vbuf  = (unsigned short*)(ws + 111149056);    // 2*4*2048*256 (tiled)
  unsigned short* attnb = (unsigned short*)(ws + 119537664);    // 4096x2048 bf16
  // total: 136,314,880 B

  // 1) merged casts (one launch)
  cvt_all_kernel<<<25600, 256, 0, stream>>>(hid, Wq, Wk, Wv, Wo, Xbf, Wcat, Wob);
  // 2) fused QKV projection + RMSNorm + RoPE -> qbuf/kbuf/vbuf directly (256 blocks)
  gemm8p<1><<<256, 512, 0, stream>>>(Xbf, Wcat, nullptr, 4096, 4096, 2560, 16,
                                     cosb, sinb, qw, kw, qbuf, kbuf, vbuf);
  // 3) sliding-window flash attention (GQA-paired 8-wave, 256 blocks x 512 thr)
  attn_kernel<<<256, 512, 0, stream>>>(qbuf, kbuf, vbuf, attnb);
  // 4) output projection: d_out = attn @ Wo^T (fp32 out, 160 blocks)
  gemm8p<0><<<160, 512, 0, stream>>>(attnb, Wob, (float*)d_out, 4096, 2560, 2048, 10,
                                     nullptr, nullptr, nullptr, nullptr,
                                     nullptr, nullptr, nullptr);
}